// Round 13
// baseline (434.508 us; speedup 1.0000x reference)
//
#include <hip/hip_runtime.h>
#include <math.h>

#define Dm 1024
#define Em 2048
#define Nm 16
#define DDm 64
#define Bb 2
#define Lm 1024
#define Mrows (Bb*Lm)
#define NCH 64          // scan chunks
#define CLEN 16         // steps per chunk (NCH*CLEN == Lm)
#define KS 16           // split-K for small gemm
#define KSO 4           // split-K for out gemm
#define PREPB 26112     // prep blocks in merged prep+rms kernel

typedef __attribute__((ext_vector_type(8))) short bf16x8;
typedef __attribute__((ext_vector_type(4))) float f32x4;
typedef unsigned int u32;
typedef unsigned short u16;

__device__ __forceinline__ u16 f2bf(float f) {
    union { float f; u32 u; } v; v.f = f;
    u32 r = v.u + 0x7fffu + ((v.u >> 16) & 1u);
    return (u16)(r >> 16);
}
__device__ __forceinline__ float bf2f(u16 v) {
    union { u32 u; float f; } t; t.u = ((u32)v) << 16; return t.f;
}

__device__ __forceinline__ void async_copy16(const void* g, void* l) {
    __builtin_amdgcn_global_load_lds(
        (const __attribute__((address_space(1))) u32*)g,
        (__attribute__((address_space(3))) u32*)l,
        16, 0, 0);
}

// ---------------- merged: weight conversions + RMSNorm ----------------
__global__ __launch_bounds__(256) void prep_rms_kernel(const float* __restrict__ skip_w,
                                                       const float* __restrict__ in_w,
                                                       const float* __restrict__ out_w,
                                                       const float* __restrict__ wd2_w,
                                                       const float* __restrict__ wb,
                                                       const float* __restrict__ wc,
                                                       const float* __restrict__ wd1,
                                                       const float* __restrict__ resid,
                                                       const float* __restrict__ norm_w,
                                                       u16* __restrict__ skip_w_bf,
                                                       u16* __restrict__ in_w_bf,
                                                       u16* __restrict__ out_w_bf,
                                                       u16* __restrict__ wd2_bf,
                                                       u16* __restrict__ wtb,
                                                       u16* __restrict__ x) {
    if (blockIdx.x < PREPB) {
        const int R0 = 2097152, R1 = 4194304, R2 = 6291456, R3 = 6422528, R4 = 6684672;
        int i = blockIdx.x * 256 + threadIdx.x;
        if (i < R0) skip_w_bf[i] = f2bf(skip_w[i]);
        else if (i < R1) in_w_bf[i - R0] = f2bf(in_w[i - R0]);
        else if (i < R2) out_w_bf[i - R1] = f2bf(out_w[i - R1]);
        else if (i < R3) wd2_bf[i - R2] = f2bf(wd2_w[i - R2]);
        else if (i < R4) {
            int j = i - R3;
            int c = j >> 11, k = j & 2047;
            float v = 0.f;
            if (c < 16) v = wb[(size_t)c * Em + k];
            else if (c < 32) v = wc[(size_t)(c - 16) * Em + k];
            else if (c < 96) v = wd1[(size_t)(c - 32) * Em + k];
            wtb[j] = f2bf(v);
        }
        return;
    }
    int row = blockIdx.x - PREPB;
    const float* r = resid + (size_t)row * Dm;
    float s = 0.f;
    for (int i = threadIdx.x; i < Dm; i += 256) { float v = r[i]; s += v * v; }
    __shared__ float red[4];
    for (int off = 32; off; off >>= 1) s += __shfl_down(s, off, 64);
    if ((threadIdx.x & 63) == 0) red[threadIdx.x >> 6] = s;
    __syncthreads();
    if (threadIdx.x == 0) {
        float t = red[0] + red[1] + red[2] + red[3];
        red[0] = rsqrtf(t / (float)Dm + 1e-5f);
    }
    __syncthreads();
    float sc = red[0];
    u16* xo = x + (size_t)row * Dm;
    for (int i = threadIdx.x; i < Dm; i += 256) xo[i] = f2bf(r[i] * sc * norm_w[i]);
}

// ===== XOR-swizzle: LDS row = 64B; physical chunk p of row r holds global
// chunk p^((r>>1)&3). Stage lane fetches global chunk (lane&3)^((lane>>3)&3);
// fragment read uses lq^((lm>>1)&3). Conflict-free (verified R6: 3.1M -> 0).

// ---------------- 128x64 tile, double-buffered (for K >= 512) ----------------
// act: 0 = fp32 out, 2 = bf16 out. klen per z-slice; z offset = z*M*ldc elems.
// C2: cols >= split go to C2 (ldc = split).
__global__ __launch_bounds__(256) void gemm_db(const u16* __restrict__ A,
                                               const u16* __restrict__ W,
                                               const float* __restrict__ bias,
                                               float* __restrict__ C,
                                               float* __restrict__ C2, int split,
                                               int M, int N, int lda, int klen, int act) {
    __shared__ __align__(16) u16 As[2][128 * 32];
    __shared__ __align__(16) u16 Ws[2][64 * 32];
    int tid = threadIdx.x;
    int lane = tid & 63, wave = tid >> 6;
    int bm = blockIdx.y * 128, bn = blockIdx.x * 64;
    int kbase = blockIdx.z * klen;
    int lm = lane & 15, lq = lane >> 4;
    int wm = (wave & 1) * 64, wn = (wave >> 1) * 32;

    f32x4 acc[4][2] = {};
    int ldrow = lane >> 2;
    int gchunk = ((lane & 3) ^ ((lane >> 3) & 3)) * 8;
    int rdoff = (lq ^ ((lm >> 1) & 3)) * 8;

    const u16* Arow0 = A + (size_t)(bm + wave * 16 + ldrow) * lda + gchunk;
    const u16* Arow1 = A + (size_t)(bm + 64 + wave * 16 + ldrow) * lda + gchunk;
    const u16* Wrow  = W + (size_t)(bn + wave * 16 + ldrow) * lda + gchunk;
    int ldsA = (wave * 16) * 32;
    int ldsA2 = (64 + wave * 16) * 32;

    int nIter = klen / 32;
    async_copy16(Arow0 + kbase, &As[0][ldsA]);
    async_copy16(Arow1 + kbase, &As[0][ldsA2]);
    async_copy16(Wrow + kbase, &Ws[0][ldsA]);
    __syncthreads();

    for (int it = 0; it < nIter; ++it) {
        int cur = it & 1, nxt = cur ^ 1;
        if (it + 1 < nIter) {
            int k0 = kbase + (it + 1) * 32;
            async_copy16(Arow0 + k0, &As[nxt][ldsA]);
            async_copy16(Arow1 + k0, &As[nxt][ldsA2]);
            async_copy16(Wrow + k0, &Ws[nxt][ldsA]);
        }
        bf16x8 a[4], b[2];
        #pragma unroll
        for (int mi = 0; mi < 4; ++mi)
            a[mi] = *(const bf16x8*)&As[cur][(wm + mi * 16 + lm) * 32 + rdoff];
        #pragma unroll
        for (int nj = 0; nj < 2; ++nj)
            b[nj] = *(const bf16x8*)&Ws[cur][(wn + nj * 16 + lm) * 32 + rdoff];
        #pragma unroll
        for (int mi = 0; mi < 4; ++mi)
            #pragma unroll
            for (int nj = 0; nj < 2; ++nj)
                acc[mi][nj] = __builtin_amdgcn_mfma_f32_16x16x32_bf16(a[mi], b[nj], acc[mi][nj], 0, 0, 0);
        __syncthreads();
    }

    int ldc = C2 ? split : N;
    size_t zoff = (size_t)blockIdx.z * M * ldc;
    #pragma unroll
    for (int nj = 0; nj < 2; ++nj) {
        int col = bn + wn + nj * 16 + lm;
        float bv = bias ? bias[col] : 0.f;
        float* Cp = C; int colw = col;
        if (C2 && col >= split) { Cp = C2; colw = col - split; }
        #pragma unroll
        for (int mi = 0; mi < 4; ++mi) {
            #pragma unroll
            for (int r = 0; r < 4; ++r) {
                int row = bm + wm + mi * 16 + lq * 4 + r;
                float v = acc[mi][nj][r] + bv;
                size_t off = zoff + (size_t)row * ldc + colw;
                if (act == 2) ((u16*)Cp)[off] = f2bf(v);
                else Cp[off] = v;
            }
        }
    }
}

// ---------------- tiny-K GEMM (K <= 128): stage ALL slices, ONE barrier ----------------
__global__ __launch_bounds__(256) void gemm_smallk(const u16* __restrict__ A,
                                                   const u16* __restrict__ W,
                                                   const float* __restrict__ bias,
                                                   u16* __restrict__ C,
                                                   int M, int N, int lda, int klen, int act) {
    __shared__ __align__(16) u16 As[4][128 * 32];
    __shared__ __align__(16) u16 Ws[4][64 * 32];
    int tid = threadIdx.x;
    int lane = tid & 63, wave = tid >> 6;
    int bm = blockIdx.y * 128, bn = blockIdx.x * 64;
    int kbase = blockIdx.z * klen;
    int lm = lane & 15, lq = lane >> 4;
    int wm = (wave & 1) * 64, wn = (wave >> 1) * 32;

    f32x4 acc[4][2] = {};
    int ldrow = lane >> 2;
    int gchunk = ((lane & 3) ^ ((lane >> 3) & 3)) * 8;
    int rdoff = (lq ^ ((lm >> 1) & 3)) * 8;

    const u16* Arow0 = A + (size_t)(bm + wave * 16 + ldrow) * lda + gchunk;
    const u16* Arow1 = A + (size_t)(bm + 64 + wave * 16 + ldrow) * lda + gchunk;
    const u16* Wrow  = W + (size_t)(bn + wave * 16 + ldrow) * lda + gchunk;
    int ldsA = (wave * 16) * 32;
    int ldsA2 = (64 + wave * 16) * 32;

    int nIter = klen / 32;        // <= 4
    for (int it = 0; it < nIter; ++it) {
        int k0 = kbase + it * 32;
        async_copy16(Arow0 + k0, &As[it][ldsA]);
        async_copy16(Arow1 + k0, &As[it][ldsA2]);
        async_copy16(Wrow + k0, &Ws[it][ldsA]);
    }
    __syncthreads();

    for (int it = 0; it < nIter; ++it) {
        bf16x8 a[4], b[2];
        #pragma unroll
        for (int mi = 0; mi < 4; ++mi)
            a[mi] = *(const bf16x8*)&As[it][(wm + mi * 16 + lm) * 32 + rdoff];
        #pragma unroll
        for (int nj = 0; nj < 2; ++nj)
            b[nj] = *(const bf16x8*)&Ws[it][(wn + nj * 16 + lm) * 32 + rdoff];
        #pragma unroll
        for (int mi = 0; mi < 4; ++mi)
            #pragma unroll
            for (int nj = 0; nj < 2; ++nj)
                acc[mi][nj] = __builtin_amdgcn_mfma_f32_16x16x32_bf16(a[mi], b[nj], acc[mi][nj], 0, 0, 0);
    }

    size_t zoff = (size_t)blockIdx.z * M * N;
    #pragma unroll
    for (int nj = 0; nj < 2; ++nj) {
        int col = bn + wn + nj * 16 + lm;
        float bv = bias ? bias[col] : 0.f;
        #pragma unroll
        for (int mi = 0; mi < 4; ++mi) {
            #pragma unroll
            for (int r = 0; r < 4; ++r) {
                int row = bm + wm + mi * 16 + lq * 4 + r;
                float v = acc[mi][nj][r] + bv;
                if (act == 1)
                    v = fmaxf(v, 0.f) + __logf(1.f + __expf(-fabsf(v)));
                C[zoff + (size_t)row * N + col] = f2bf(v);
            }
        }
    }
}

// ---------------- out = resid + sum_ks bf16 OutPart[ks] ----------------
__global__ __launch_bounds__(256) void out_reduce_kernel(const u16* __restrict__ part,
                                                         const float* __restrict__ resid,
                                                         float* __restrict__ out) {
    int idx = blockIdx.x * 256 + threadIdx.x;
    float4 s = ((const float4*)resid)[idx];
    const int planeQ = Mrows * Dm / 4;
    #pragma unroll
    for (int ks = 0; ks < KSO; ++ks) {
        ushort4 p = ((const ushort4*)part)[(size_t)ks * planeQ + idx];
        s.x += bf2f(p.x); s.y += bf2f(p.y); s.z += bf2f(p.z); s.w += bf2f(p.w);
    }
    ((float4*)out)[idx] = s;
}

// reduce bf16 split-K partials -> Bm, Cm (fp32), d1 (bf16)
__global__ __launch_bounds__(256) void small_reduce_kernel(const u16* __restrict__ Cp,
                                                           float* __restrict__ Bm,
                                                           float* __restrict__ Cm,
                                                           u16* __restrict__ d1) {
    int idx = blockIdx.x * 256 + threadIdx.x;
    int row = idx >> 7, col = idx & 127;
    float s = 0.f;
    #pragma unroll
    for (int ks = 0; ks < KS; ++ks) s += bf2f(Cp[(size_t)ks * (Mrows * 128) + idx]);
    if (col < 16) Bm[(size_t)row * 16 + col] = s;
    else if (col < 32) Cm[(size_t)row * 16 + (col - 16)] = s;
    else if (col < 96) d1[(size_t)row * 64 + (col - 32)] = f2bf(s);
}

// ---------------- Depthwise causal conv (K=4) + bias + SiLU, bf16 in/out ----------------
__global__ __launch_bounds__(256) void conv_silu_kernel(const u16* __restrict__ xi,
                                                        const float* __restrict__ cw,
                                                        const float* __restrict__ cb,
                                                        u16* __restrict__ x2b, int total) {
    int idx = blockIdx.x * 256 + threadIdx.x;
    if (idx >= total) return;
    int e = idx & (Em - 1);
    int l = (idx >> 11) & (Lm - 1);
    const u16* base = xi + idx;
    float w0 = cw[e * 4 + 0], w1 = cw[e * 4 + 1], w2 = cw[e * 4 + 2], w3 = cw[e * 4 + 3];
    float acc = cb[e];
    if (l >= 3) acc += w0 * bf2f(base[-3 * Em]);
    if (l >= 2) acc += w1 * bf2f(base[-2 * Em]);
    if (l >= 1) acc += w2 * bf2f(base[-1 * Em]);
    acc += w3 * bf2f(base[0]);
    float v = acc / (1.f + __expf(-acc));
    x2b[idx] = f2bf(v);
}

// ======================= Chunked selective scan =======================
// 1024 blocks (4/CU), CLEN=16, depth-2 software pipeline on all streamed loads.
__global__ __launch_bounds__(256) void scan1_kernel(const u16* __restrict__ delta,
                                                    const u16* __restrict__ x2b,
                                                    const float* __restrict__ Bm,
                                                    const float* __restrict__ A_log,
                                                    float* __restrict__ h_end,
                                                    float* __restrict__ P) {
    int e = (blockIdx.x & 7) * 256 + threadIdx.x;
    int bc = blockIdx.x >> 3;
    int b = bc & 1, c = bc >> 1;        // c in 0..NCH-1
    float A[16];
    {
        const float4* al = (const float4*)(A_log + e * 16);
        float4 q0 = al[0], q1 = al[1], q2 = al[2], q3 = al[3];
        A[0]=-expf(q0.x); A[1]=-expf(q0.y); A[2]=-expf(q0.z); A[3]=-expf(q0.w);
        A[4]=-expf(q1.x); A[5]=-expf(q1.y); A[6]=-expf(q1.z); A[7]=-expf(q1.w);
        A[8]=-expf(q2.x); A[9]=-expf(q2.y); A[10]=-expf(q2.z); A[11]=-expf(q2.w);
        A[12]=-expf(q3.x); A[13]=-expf(q3.y); A[14]=-expf(q3.z); A[15]=-expf(q3.w);
    }
    float h[16], Pr[16];
    #pragma unroll
    for (int k = 0; k < 16; ++k) { h[k] = 0.f; Pr[k] = 1.f; }

    int l0 = c * CLEN;
    const u16* dp  = delta + ((size_t)(b * Lm + l0)) * Em + e;
    const u16* xp  = x2b   + ((size_t)(b * Lm + l0)) * Em + e;
    const float* bp = Bm   + ((size_t)(b * Lm + l0)) * Nm;

    float dv[2], xv[2];
    float4 bq[2][4];
    #pragma unroll
    for (int s = 0; s < 2; ++s) {
        dv[s] = bf2f(dp[(size_t)s * Em]);
        xv[s] = bf2f(xp[(size_t)s * Em]);
        const float* nb = bp + (size_t)s * Nm;
        bq[s][0] = *(const float4*)(nb); bq[s][1] = *(const float4*)(nb + 4);
        bq[s][2] = *(const float4*)(nb + 8); bq[s][3] = *(const float4*)(nb + 12);
    }

    #pragma unroll 1
    for (int l = 0; l < CLEN; ++l) {
        int cur = l & 1;
        float d = dv[cur], xvv = xv[cur];
        float4 b0 = bq[cur][0], b1 = bq[cur][1], b2 = bq[cur][2], b3 = bq[cur][3];
        if (l + 2 < CLEN) {
            size_t lo = (size_t)(l + 2);
            dv[cur] = bf2f(dp[lo * Em]);
            xv[cur] = bf2f(xp[lo * Em]);
            const float* nb = bp + lo * Nm;
            bq[cur][0] = *(const float4*)(nb); bq[cur][1] = *(const float4*)(nb + 4);
            bq[cur][2] = *(const float4*)(nb + 8); bq[cur][3] = *(const float4*)(nb + 12);
        }
        float dx = d * xvv;
        float bb[16] = {b0.x,b0.y,b0.z,b0.w, b1.x,b1.y,b1.z,b1.w,
                        b2.x,b2.y,b2.z,b2.w, b3.x,b3.y,b3.z,b3.w};
        #pragma unroll
        for (int k = 0; k < 16; ++k) {
            float a = __expf(d * A[k]);
            h[k] = a * h[k] + bb[k] * dx;
            Pr[k] *= a;
        }
    }
    size_t base = (((size_t)c * 2 + b) * 16) * 2048 + e;
    #pragma unroll
    for (int k = 0; k < 16; ++k) {
        h_end[base + k * 2048] = h[k];
        P[base + k * 2048] = Pr[k];
    }
}

__global__ __launch_bounds__(256) void scan2_kernel(float* __restrict__ h_end,
                                                    const float* __restrict__ P) {
    int T = blockIdx.x * 256 + threadIdx.x;
    float hi = 0.f;
    float he_n = h_end[T], p_n = P[T];
    #pragma unroll 1
    for (int c = 0; c < NCH; ++c) {
        float he = he_n, p = p_n;
        if (c < NCH - 1) {
            he_n = h_end[(size_t)(c + 1) * 65536 + T];
            p_n  = P[(size_t)(c + 1) * 65536 + T];
        }
        float hnew = fmaf(p, hi, he);
        h_end[(size_t)c * 65536 + T] = hi;
        hi = hnew;
    }
}

__global__ __launch_bounds__(256) void scan3_kernel(const u16* __restrict__ delta,
                                                    const u16* __restrict__ x2b,
                                                    const float* __restrict__ Bm,
                                                    const float* __restrict__ Cm,
                                                    const float* __restrict__ A_log,
                                                    const float* __restrict__ h_init,
                                                    const u16* __restrict__ skip,
                                                    const float* __restrict__ W_D,
                                                    u16* __restrict__ yb) {
    int e = (blockIdx.x & 7) * 256 + threadIdx.x;
    int bc = blockIdx.x >> 3;
    int b = bc & 1, c = bc >> 1;
    float A[16];
    {
        const float4* al = (const float4*)(A_log + e * 16);
        float4 q0 = al[0], q1 = al[1], q2 = al[2], q3 = al[3];
        A[0]=-expf(q0.x); A[1]=-expf(q0.y); A[2]=-expf(q0.z); A[3]=-expf(q0.w);
        A[4]=-expf(q1.x); A[5]=-expf(q1.y); A[6]=-expf(q1.z); A[7]=-expf(q1.w);
        A[8]=-expf(q2.x); A[9]=-expf(q2.y); A[10]=-expf(q2.z); A[11]=-expf(q2.w);
        A[12]=-expf(q3.x); A[13]=-expf(q3.y); A[14]=-expf(q3.z); A[15]=-expf(q3.w);
    }
    float h[16];
    {
        size_t base = (((size_t)c * 2 + b) * 16) * 2048 + e;
        #pragma unroll
        for (int k = 0; k < 16; ++k) h[k] = h_init[base + k * 2048];
    }
    float wd = W_D[e];

    int l0 = c * CLEN;
    const u16* dp  = delta + ((size_t)(b * Lm + l0)) * Em + e;
    const u16* xp  = x2b   + ((size_t)(b * Lm + l0)) * Em + e;
    const u16* sp  = skip  + ((size_t)(b * Lm + l0)) * Em + e;
    const float* bp = Bm   + ((size_t)(b * Lm + l0)) * Nm;
    const float* cp = Cm   + ((size_t)(b * Lm + l0)) * Nm;
    u16* yp = yb + ((size_t)(b * Lm + l0)) * Em + e;

    float dv[2], xv[2], sv2[2];
    float4 bq[2][4], cq[2][4];
    #pragma unroll
    for (int s = 0; s < 2; ++s) {
        dv[s] = bf2f(dp[(size_t)s * Em]);
        xv[s] = bf2f(xp[(size_t)s * Em]);
        sv2[s] = bf2f(sp[(size_t)s * Em]);
        const float* nb = bp + (size_t)s * Nm;
        bq[s][0] = *(const float4*)(nb); bq[s][1] = *(const float4*)(nb + 4);
        bq[s][2] = *(const float4*)(nb + 8); bq[s][3] = *(const float4*)(nb + 12);
        const float* nc = cp + (size_t)s * Nm;
        cq[s][0] = *(const float4*)(nc); cq[s][1] = *(const float4*)(nc + 4);
        cq[s][2] = *(const float4*)(nc + 8); cq[s][3] = *(const float4*)(nc + 12);
    }

    #pragma unroll 1
    for (int l = 0; l < CLEN; ++l) {
        int cur = l & 1;
        float d = dv[cur], xvv = xv[cur], sv = sv2[cur];
        float4 b0 = bq[cur][0], b1 = bq[cur][1], b2 = bq[cur][2], b3 = bq[cur][3];
        float4 c0 = cq[cur][0], c1 = cq[cur][1], c2 = cq[cur][2], c3 = cq[cur][3];
        if (l + 2 < CLEN) {
            size_t lo = (size_t)(l + 2);
            dv[cur] = bf2f(dp[lo * Em]);
            xv[cur] = bf2f(xp[lo * Em]);
            sv2[cur] = bf2f(sp[lo * Em]);
            const float* nb = bp + lo * Nm;
            bq[cur][0] = *(const float4*)(nb); bq[cur][1] = *(const float4*)(nb + 4);
            bq[cur][2] = *(const float4*)(nb + 8); bq[cur][3] = *(const float4*)(nb + 12);
            const float* nc = cp + lo * Nm;
            cq[cur][0] = *(const float4*)(nc); cq[cur][1] = *(const float4*)(nc + 4);
            cq[cur][2] = *(const float4*)(nc + 8); cq[cur][3] = *(const float4*)(nc + 12);
        }
        float dx = d * xvv;
        float bb[16] = {b0.x,b0.y,b0.z,b0.w, b1.x,b1.y,b1.z,b1.w,
                        b2.x,b2.y,b2.z,b2.w, b3.x,b3.y,b3.z,b3.w};
        float cc[16] = {c0.x,c0.y,c0.z,c0.w, c1.x,c1.y,c1.z,c1.w,
                        c2.x,c2.y,c2.z,c2.w, c3.x,c3.y,c3.z,c3.w};
        float yv = 0.f;
        #pragma unroll
        for (int k = 0; k < 16; ++k) {
            float a = __expf(d * A[k]);
            h[k] = a * h[k] + bb[k] * dx;
            yv += h[k] * cc[k];
        }
        float sig = 1.f / (1.f + __expf(-sv));
        yp[(size_t)l * Em] = f2bf((yv + xvv * wd) * (sv * sig));
    }
}

extern "C" void kernel_launch(void* const* d_in, const int* in_sizes, int n_in,
                              void* d_out, int out_size, void* d_ws, size_t ws_size,
                              hipStream_t stream) {
    const float* resid  = (const float*)d_in[0];
    const float* norm_w = (const float*)d_in[2];
    const float* skip_w = (const float*)d_in[3];
    const float* in_w   = (const float*)d_in[4];
    const float* conv_w = (const float*)d_in[5];
    const float* conv_b = (const float*)d_in[6];
    const float* wd1    = (const float*)d_in[7];
    const float* wd2_w  = (const float*)d_in[8];
    const float* wd2_b  = (const float*)d_in[9];
    const float* wb     = (const float*)d_in[10];
    const float* wc     = (const float*)d_in[11];
    const float* A_log  = (const float*)d_in[12];
    const float* W_D    = (const float*)d_in[13];
    const float* out_w  = (const float*)d_in[14];
    float* out = (float*)d_out;

    float* ws = (float*)d_ws;
    float* region0 = ws; ws += 3 * 1024 * 1024;
    u16* x_bf      = (u16*)region0;
    u16* skip_w_bf = (u16*)(region0 + 1024 * 1024);
    u16* in_w_bf   = (u16*)(region0 + 2 * 1024 * 1024);
    u16* out_w_bf  = (u16*)ws; ws += 1024 * 1024;
    u16* wd2_bf    = (u16*)ws; ws += 65536;
    u16* d1_bf     = (u16*)ws; ws += 65536;
    u16* wtb       = (u16*)ws; ws += 131072;       // [128][2048] bf16
    float* h_endb  = ws; ws += 4 * 1024 * 1024;    // [NCH=64][B][16][E]
    float* Pbuf    = ws; ws += 4 * 1024 * 1024;
    u16* Cpart16   = (u16*)ws; ws += (size_t)KS * Mrows * 128 / 2;   // bf16 partials
    u16* skip_bf   = (u16*)ws; ws += (size_t)Mrows * Em / 2;
    u16* xi_bf     = (u16*)ws; ws += (size_t)Mrows * Em / 2;         // reused as delta
    u16* x2_bf     = (u16*)ws; ws += (size_t)Mrows * Em / 2;
    u16* yb_bf     = (u16*)ws; ws += (size_t)Mrows * Em / 2;
    u16* OutPart16 = (u16*)ws; ws += (size_t)KSO * Mrows * Dm / 2;   // bf16 partials
    float* Bmb     = ws; ws += (size_t)Mrows * Nm;
    float* Cmb     = ws; ws += (size_t)Mrows * Nm;
    u16* delta16   = xi_bf;   // xi dead after conv

    const int M = Mrows;

    // merged weight prep + rmsnorm (one dispatch)
    prep_rms_kernel<<<PREPB + M, 256, 0, stream>>>(
        skip_w, in_w, out_w, wd2_w, wb, wc, wd1, resid, norm_w,
        skip_w_bf, in_w_bf, out_w_bf, wd2_bf, wtb, x_bf);

    // fused: [skip | xi] = x @ [skip_w; in_w]^T  (128x64 db, 1024 blocks, bf16 out)
    gemm_db<<<dim3(2 * Em / 64, M / 128, 1), 256, 0, stream>>>(
        x_bf, skip_w_bf, nullptr, (float*)skip_bf, (float*)xi_bf, Em, M, 2 * Em, Dm, Dm, 2);

    conv_silu_kernel<<<(M * Em) / 256, 256, 0, stream>>>(xi_bf, conv_w, conv_b, x2_bf, M * Em);

    // Bm/Cm/d1: x2 @ wtb^T, split-K=16, tiny-K path (4 stages, 1 barrier)
    gemm_smallk<<<dim3(128 / 64, M / 128, KS), 256, 0, stream>>>(
        x2_bf, wtb, nullptr, Cpart16, M, 128, Em, Em / KS, 0);
    small_reduce_kernel<<<(M * 128) / 256, 256, 0, stream>>>(Cpart16, Bmb, Cmb, d1_bf);

    // delta = softplus(d1 @ wd2^T + b), tiny-K path (2 stages, 1 barrier), bf16 out
    gemm_smallk<<<dim3(Em / 64, M / 128, 1), 256, 0, stream>>>(
        d1_bf, wd2_bf, wd2_b, delta16, M, Em, DDm, DDm, 1);

    // chunked scan: 1024 blocks each for scan1/scan3 (CLEN=16, NCH=64)
    scan1_kernel<<<Bb * NCH * 8, 256, 0, stream>>>(delta16, x2_bf, Bmb, A_log, h_endb, Pbuf);
    scan2_kernel<<<65536 / 256, 256, 0, stream>>>(h_endb, Pbuf);
    scan3_kernel<<<Bb * NCH * 8, 256, 0, stream>>>(delta16, x2_bf, Bmb, Cmb, A_log, h_endb,
                                                   skip_bf, W_D, yb_bf);

    // out partials: yb @ out_w^T, split-K=4 via z, bf16 partials
    gemm_db<<<dim3(Dm / 64, M / 128, KSO), 256, 0, stream>>>(
        yb_bf, out_w_bf, nullptr, (float*)OutPart16, nullptr, 0, M, Dm, Em, Em / KSO, 2);
    out_reduce_kernel<<<(M * Dm / 4) / 256, 256, 0, stream>>>(OutPart16, resid, out);
}

// Round 14
// 260.183 us; speedup vs baseline: 1.6700x; 1.6700x over previous
//
#include <hip/hip_runtime.h>
#include <math.h>

#define Dm 1024
#define Em 2048
#define Nm 16
#define DDm 64
#define Bb 2
#define Lm 1024
#define Mrows (Bb*Lm)
#define NCH 64          // scan chunks
#define CLEN 16         // steps per chunk (NCH*CLEN == Lm)
#define KS 16           // split-K for small gemm
#define KSO 4           // split-K for out gemm
#define PREPB 26112     // prep blocks in merged prep+rms kernel

typedef __attribute__((ext_vector_type(8))) short bf16x8;
typedef __attribute__((ext_vector_type(4))) float f32x4;
typedef unsigned int u32;
typedef unsigned short u16;

__device__ __forceinline__ u16 f2bf(float f) {
    union { float f; u32 u; } v; v.f = f;
    u32 r = v.u + 0x7fffu + ((v.u >> 16) & 1u);
    return (u16)(r >> 16);
}
__device__ __forceinline__ float bf2f(u16 v) {
    union { u32 u; float f; } t; t.u = ((u32)v) << 16; return t.f;
}

__device__ __forceinline__ void async_copy16(const void* g, void* l) {
    __builtin_amdgcn_global_load_lds(
        (const __attribute__((address_space(1))) u32*)g,
        (__attribute__((address_space(3))) u32*)l,
        16, 0, 0);
}

// ---------------- merged: weight conversions + RMSNorm ----------------
__global__ __launch_bounds__(256) void prep_rms_kernel(const float* __restrict__ skip_w,
                                                       const float* __restrict__ in_w,
                                                       const float* __restrict__ out_w,
                                                       const float* __restrict__ wd2_w,
                                                       const float* __restrict__ wb,
                                                       const float* __restrict__ wc,
                                                       const float* __restrict__ wd1,
                                                       const float* __restrict__ resid,
                                                       const float* __restrict__ norm_w,
                                                       u16* __restrict__ skip_w_bf,
                                                       u16* __restrict__ in_w_bf,
                                                       u16* __restrict__ out_w_bf,
                                                       u16* __restrict__ wd2_bf,
                                                       u16* __restrict__ wtb,
                                                       u16* __restrict__ x) {
    if (blockIdx.x < PREPB) {
        const int R0 = 2097152, R1 = 4194304, R2 = 6291456, R3 = 6422528, R4 = 6684672;
        int i = blockIdx.x * 256 + threadIdx.x;
        if (i < R0) skip_w_bf[i] = f2bf(skip_w[i]);
        else if (i < R1) in_w_bf[i - R0] = f2bf(in_w[i - R0]);
        else if (i < R2) out_w_bf[i - R1] = f2bf(out_w[i - R1]);
        else if (i < R3) wd2_bf[i - R2] = f2bf(wd2_w[i - R2]);
        else if (i < R4) {
            int j = i - R3;
            int c = j >> 11, k = j & 2047;
            float v = 0.f;
            if (c < 16) v = wb[(size_t)c * Em + k];
            else if (c < 32) v = wc[(size_t)(c - 16) * Em + k];
            else if (c < 96) v = wd1[(size_t)(c - 32) * Em + k];
            wtb[j] = f2bf(v);
        }
        return;
    }
    int row = blockIdx.x - PREPB;
    const float* r = resid + (size_t)row * Dm;
    float s = 0.f;
    for (int i = threadIdx.x; i < Dm; i += 256) { float v = r[i]; s += v * v; }
    __shared__ float red[4];
    for (int off = 32; off; off >>= 1) s += __shfl_down(s, off, 64);
    if ((threadIdx.x & 63) == 0) red[threadIdx.x >> 6] = s;
    __syncthreads();
    if (threadIdx.x == 0) {
        float t = red[0] + red[1] + red[2] + red[3];
        red[0] = rsqrtf(t / (float)Dm + 1e-5f);
    }
    __syncthreads();
    float sc = red[0];
    u16* xo = x + (size_t)row * Dm;
    for (int i = threadIdx.x; i < Dm; i += 256) xo[i] = f2bf(r[i] * sc * norm_w[i]);
}

// ===== XOR-swizzle: LDS row = 64B; physical chunk p of row r holds global
// chunk p^((r>>1)&3). Stage lane fetches global chunk (lane&3)^((lane>>3)&3);
// fragment read uses lq^((lm>>1)&3). Conflict-free (verified R6: 3.1M -> 0).

// ---------------- 128x64 tile, double-buffered (for K >= 512) ----------------
__global__ __launch_bounds__(256) void gemm_db(const u16* __restrict__ A,
                                               const u16* __restrict__ W,
                                               const float* __restrict__ bias,
                                               float* __restrict__ C,
                                               float* __restrict__ C2, int split,
                                               int M, int N, int lda, int klen, int act) {
    __shared__ __align__(16) u16 As[2][128 * 32];
    __shared__ __align__(16) u16 Ws[2][64 * 32];
    int tid = threadIdx.x;
    int lane = tid & 63, wave = tid >> 6;
    int bm = blockIdx.y * 128, bn = blockIdx.x * 64;
    int kbase = blockIdx.z * klen;
    int lm = lane & 15, lq = lane >> 4;
    int wm = (wave & 1) * 64, wn = (wave >> 1) * 32;

    f32x4 acc[4][2] = {};
    int ldrow = lane >> 2;
    int gchunk = ((lane & 3) ^ ((lane >> 3) & 3)) * 8;
    int rdoff = (lq ^ ((lm >> 1) & 3)) * 8;

    const u16* Arow0 = A + (size_t)(bm + wave * 16 + ldrow) * lda + gchunk;
    const u16* Arow1 = A + (size_t)(bm + 64 + wave * 16 + ldrow) * lda + gchunk;
    const u16* Wrow  = W + (size_t)(bn + wave * 16 + ldrow) * lda + gchunk;
    int ldsA = (wave * 16) * 32;
    int ldsA2 = (64 + wave * 16) * 32;

    int nIter = klen / 32;
    async_copy16(Arow0 + kbase, &As[0][ldsA]);
    async_copy16(Arow1 + kbase, &As[0][ldsA2]);
    async_copy16(Wrow + kbase, &Ws[0][ldsA]);
    __syncthreads();

    for (int it = 0; it < nIter; ++it) {
        int cur = it & 1, nxt = cur ^ 1;
        if (it + 1 < nIter) {
            int k0 = kbase + (it + 1) * 32;
            async_copy16(Arow0 + k0, &As[nxt][ldsA]);
            async_copy16(Arow1 + k0, &As[nxt][ldsA2]);
            async_copy16(Wrow + k0, &Ws[nxt][ldsA]);
        }
        bf16x8 a[4], b[2];
        #pragma unroll
        for (int mi = 0; mi < 4; ++mi)
            a[mi] = *(const bf16x8*)&As[cur][(wm + mi * 16 + lm) * 32 + rdoff];
        #pragma unroll
        for (int nj = 0; nj < 2; ++nj)
            b[nj] = *(const bf16x8*)&Ws[cur][(wn + nj * 16 + lm) * 32 + rdoff];
        #pragma unroll
        for (int mi = 0; mi < 4; ++mi)
            #pragma unroll
            for (int nj = 0; nj < 2; ++nj)
                acc[mi][nj] = __builtin_amdgcn_mfma_f32_16x16x32_bf16(a[mi], b[nj], acc[mi][nj], 0, 0, 0);
        __syncthreads();
    }

    int ldc = C2 ? split : N;
    size_t zoff = (size_t)blockIdx.z * M * ldc;
    #pragma unroll
    for (int nj = 0; nj < 2; ++nj) {
        int col = bn + wn + nj * 16 + lm;
        float bv = bias ? bias[col] : 0.f;
        float* Cp = C; int colw = col;
        if (C2 && col >= split) { Cp = C2; colw = col - split; }
        #pragma unroll
        for (int mi = 0; mi < 4; ++mi) {
            #pragma unroll
            for (int r = 0; r < 4; ++r) {
                int row = bm + wm + mi * 16 + lq * 4 + r;
                float v = acc[mi][nj][r] + bv;
                size_t off = zoff + (size_t)row * ldc + colw;
                if (act == 2) ((u16*)Cp)[off] = f2bf(v);
                else Cp[off] = v;
            }
        }
    }
}

// ---------------- tiny-K GEMM (K <= 128): stage ALL slices, ONE barrier ----------------
__global__ __launch_bounds__(256) void gemm_smallk(const u16* __restrict__ A,
                                                   const u16* __restrict__ W,
                                                   const float* __restrict__ bias,
                                                   u16* __restrict__ C,
                                                   int M, int N, int lda, int klen, int act) {
    __shared__ __align__(16) u16 As[4][128 * 32];
    __shared__ __align__(16) u16 Ws[4][64 * 32];
    int tid = threadIdx.x;
    int lane = tid & 63, wave = tid >> 6;
    int bm = blockIdx.y * 128, bn = blockIdx.x * 64;
    int kbase = blockIdx.z * klen;
    int lm = lane & 15, lq = lane >> 4;
    int wm = (wave & 1) * 64, wn = (wave >> 1) * 32;

    f32x4 acc[4][2] = {};
    int ldrow = lane >> 2;
    int gchunk = ((lane & 3) ^ ((lane >> 3) & 3)) * 8;
    int rdoff = (lq ^ ((lm >> 1) & 3)) * 8;

    const u16* Arow0 = A + (size_t)(bm + wave * 16 + ldrow) * lda + gchunk;
    const u16* Arow1 = A + (size_t)(bm + 64 + wave * 16 + ldrow) * lda + gchunk;
    const u16* Wrow  = W + (size_t)(bn + wave * 16 + ldrow) * lda + gchunk;
    int ldsA = (wave * 16) * 32;
    int ldsA2 = (64 + wave * 16) * 32;

    int nIter = klen / 32;        // <= 4
    for (int it = 0; it < nIter; ++it) {
        int k0 = kbase + it * 32;
        async_copy16(Arow0 + k0, &As[it][ldsA]);
        async_copy16(Arow1 + k0, &As[it][ldsA2]);
        async_copy16(Wrow + k0, &Ws[it][ldsA]);
    }
    __syncthreads();

    for (int it = 0; it < nIter; ++it) {
        bf16x8 a[4], b[2];
        #pragma unroll
        for (int mi = 0; mi < 4; ++mi)
            a[mi] = *(const bf16x8*)&As[it][(wm + mi * 16 + lm) * 32 + rdoff];
        #pragma unroll
        for (int nj = 0; nj < 2; ++nj)
            b[nj] = *(const bf16x8*)&Ws[it][(wn + nj * 16 + lm) * 32 + rdoff];
        #pragma unroll
        for (int mi = 0; mi < 4; ++mi)
            #pragma unroll
            for (int nj = 0; nj < 2; ++nj)
                acc[mi][nj] = __builtin_amdgcn_mfma_f32_16x16x32_bf16(a[mi], b[nj], acc[mi][nj], 0, 0, 0);
    }

    size_t zoff = (size_t)blockIdx.z * M * N;
    #pragma unroll
    for (int nj = 0; nj < 2; ++nj) {
        int col = bn + wn + nj * 16 + lm;
        float bv = bias ? bias[col] : 0.f;
        #pragma unroll
        for (int mi = 0; mi < 4; ++mi) {
            #pragma unroll
            for (int r = 0; r < 4; ++r) {
                int row = bm + wm + mi * 16 + lq * 4 + r;
                float v = acc[mi][nj][r] + bv;
                if (act == 1)
                    v = fmaxf(v, 0.f) + __logf(1.f + __expf(-fabsf(v)));
                C[zoff + (size_t)row * N + col] = f2bf(v);
            }
        }
    }
}

// ---------------- out = resid + sum_ks bf16 OutPart[ks] ----------------
__global__ __launch_bounds__(256) void out_reduce_kernel(const u16* __restrict__ part,
                                                         const float* __restrict__ resid,
                                                         float* __restrict__ out) {
    int idx = blockIdx.x * 256 + threadIdx.x;
    float4 s = ((const float4*)resid)[idx];
    const int planeQ = Mrows * Dm / 4;
    #pragma unroll
    for (int ks = 0; ks < KSO; ++ks) {
        ushort4 p = ((const ushort4*)part)[(size_t)ks * planeQ + idx];
        s.x += bf2f(p.x); s.y += bf2f(p.y); s.z += bf2f(p.z); s.w += bf2f(p.w);
    }
    ((float4*)out)[idx] = s;
}

// reduce bf16 split-K partials -> Bm, Cm (fp32), d1 (bf16)
__global__ __launch_bounds__(256) void small_reduce_kernel(const u16* __restrict__ Cp,
                                                           float* __restrict__ Bm,
                                                           float* __restrict__ Cm,
                                                           u16* __restrict__ d1) {
    int idx = blockIdx.x * 256 + threadIdx.x;
    int row = idx >> 7, col = idx & 127;
    float s = 0.f;
    #pragma unroll
    for (int ks = 0; ks < KS; ++ks) s += bf2f(Cp[(size_t)ks * (Mrows * 128) + idx]);
    if (col < 16) Bm[(size_t)row * 16 + col] = s;
    else if (col < 32) Cm[(size_t)row * 16 + (col - 16)] = s;
    else if (col < 96) d1[(size_t)row * 64 + (col - 32)] = f2bf(s);
}

// ---------------- Depthwise causal conv (K=4) + bias + SiLU, bf16 in/out ----------------
__global__ __launch_bounds__(256) void conv_silu_kernel(const u16* __restrict__ xi,
                                                        const float* __restrict__ cw,
                                                        const float* __restrict__ cb,
                                                        u16* __restrict__ x2b, int total) {
    int idx = blockIdx.x * 256 + threadIdx.x;
    if (idx >= total) return;
    int e = idx & (Em - 1);
    int l = (idx >> 11) & (Lm - 1);
    const u16* base = xi + idx;
    float w0 = cw[e * 4 + 0], w1 = cw[e * 4 + 1], w2 = cw[e * 4 + 2], w3 = cw[e * 4 + 3];
    float acc = cb[e];
    if (l >= 3) acc += w0 * bf2f(base[-3 * Em]);
    if (l >= 2) acc += w1 * bf2f(base[-2 * Em]);
    if (l >= 1) acc += w2 * bf2f(base[-1 * Em]);
    acc += w3 * bf2f(base[0]);
    float v = acc / (1.f + __expf(-acc));
    x2b[idx] = f2bf(v);
}

// ======================= Chunked selective scan =======================
// 1024 blocks (4/CU), CLEN=16, depth-1 prefetch in NAMED registers (no
// dynamically-indexed arrays — R13's bq[cur] spilled to scratch: 476 MB writes).
__global__ __launch_bounds__(256) void scan1_kernel(const u16* __restrict__ delta,
                                                    const u16* __restrict__ x2b,
                                                    const float* __restrict__ Bm,
                                                    const float* __restrict__ A_log,
                                                    float* __restrict__ h_end,
                                                    float* __restrict__ P) {
    int e = (blockIdx.x & 7) * 256 + threadIdx.x;
    int bc = blockIdx.x >> 3;
    int b = bc & 1, c = bc >> 1;        // c in 0..NCH-1
    float A[16];
    {
        const float4* al = (const float4*)(A_log + e * 16);
        float4 q0 = al[0], q1 = al[1], q2 = al[2], q3 = al[3];
        A[0]=-expf(q0.x); A[1]=-expf(q0.y); A[2]=-expf(q0.z); A[3]=-expf(q0.w);
        A[4]=-expf(q1.x); A[5]=-expf(q1.y); A[6]=-expf(q1.z); A[7]=-expf(q1.w);
        A[8]=-expf(q2.x); A[9]=-expf(q2.y); A[10]=-expf(q2.z); A[11]=-expf(q2.w);
        A[12]=-expf(q3.x); A[13]=-expf(q3.y); A[14]=-expf(q3.z); A[15]=-expf(q3.w);
    }
    float h[16], Pr[16];
    #pragma unroll
    for (int k = 0; k < 16; ++k) { h[k] = 0.f; Pr[k] = 1.f; }

    int l0 = c * CLEN;
    const u16* dp  = delta + ((size_t)(b * Lm + l0)) * Em + e;
    const u16* xp  = x2b   + ((size_t)(b * Lm + l0)) * Em + e;
    const float* bp = Bm   + ((size_t)(b * Lm + l0)) * Nm;

    float d_n = bf2f(dp[0]), x_n = bf2f(xp[0]);
    float4 b0n = *(const float4*)(bp + 0), b1n = *(const float4*)(bp + 4);
    float4 b2n = *(const float4*)(bp + 8), b3n = *(const float4*)(bp + 12);

    #pragma unroll 1
    for (int l = 0; l < CLEN; ++l) {
        float d = d_n, xv = x_n;
        float4 b0 = b0n, b1 = b1n, b2 = b2n, b3 = b3n;
        if (l < CLEN - 1) {
            d_n = bf2f(dp[(size_t)(l + 1) * Em]); x_n = bf2f(xp[(size_t)(l + 1) * Em]);
            const float* nb = bp + (size_t)(l + 1) * Nm;
            b0n = *(const float4*)(nb); b1n = *(const float4*)(nb + 4);
            b2n = *(const float4*)(nb + 8); b3n = *(const float4*)(nb + 12);
        }
        float dx = d * xv;
        float bb[16] = {b0.x,b0.y,b0.z,b0.w, b1.x,b1.y,b1.z,b1.w,
                        b2.x,b2.y,b2.z,b2.w, b3.x,b3.y,b3.z,b3.w};
        #pragma unroll
        for (int k = 0; k < 16; ++k) {
            float a = __expf(d * A[k]);
            h[k] = a * h[k] + bb[k] * dx;
            Pr[k] *= a;
        }
    }
    size_t base = (((size_t)c * 2 + b) * 16) * 2048 + e;
    #pragma unroll
    for (int k = 0; k < 16; ++k) {
        h_end[base + k * 2048] = h[k];
        P[base + k * 2048] = Pr[k];
    }
}

__global__ __launch_bounds__(256) void scan2_kernel(float* __restrict__ h_end,
                                                    const float* __restrict__ P) {
    int T = blockIdx.x * 256 + threadIdx.x;
    float hi = 0.f;
    float he_n = h_end[T], p_n = P[T];
    #pragma unroll 1
    for (int c = 0; c < NCH; ++c) {
        float he = he_n, p = p_n;
        if (c < NCH - 1) {
            he_n = h_end[(size_t)(c + 1) * 65536 + T];
            p_n  = P[(size_t)(c + 1) * 65536 + T];
        }
        float hnew = fmaf(p, hi, he);
        h_end[(size_t)c * 65536 + T] = hi;
        hi = hnew;
    }
}

__global__ __launch_bounds__(256) void scan3_kernel(const u16* __restrict__ delta,
                                                    const u16* __restrict__ x2b,
                                                    const float* __restrict__ Bm,
                                                    const float* __restrict__ Cm,
                                                    const float* __restrict__ A_log,
                                                    const float* __restrict__ h_init,
                                                    const u16* __restrict__ skip,
                                                    const float* __restrict__ W_D,
                                                    u16* __restrict__ yb) {
    int e = (blockIdx.x & 7) * 256 + threadIdx.x;
    int bc = blockIdx.x >> 3;
    int b = bc & 1, c = bc >> 1;
    float A[16];
    {
        const float4* al = (const float4*)(A_log + e * 16);
        float4 q0 = al[0], q1 = al[1], q2 = al[2], q3 = al[3];
        A[0]=-expf(q0.x); A[1]=-expf(q0.y); A[2]=-expf(q0.z); A[3]=-expf(q0.w);
        A[4]=-expf(q1.x); A[5]=-expf(q1.y); A[6]=-expf(q1.z); A[7]=-expf(q1.w);
        A[8]=-expf(q2.x); A[9]=-expf(q2.y); A[10]=-expf(q2.z); A[11]=-expf(q2.w);
        A[12]=-expf(q3.x); A[13]=-expf(q3.y); A[14]=-expf(q3.z); A[15]=-expf(q3.w);
    }
    float h[16];
    {
        size_t base = (((size_t)c * 2 + b) * 16) * 2048 + e;
        #pragma unroll
        for (int k = 0; k < 16; ++k) h[k] = h_init[base + k * 2048];
    }
    float wd = W_D[e];

    int l0 = c * CLEN;
    const u16* dp  = delta + ((size_t)(b * Lm + l0)) * Em + e;
    const u16* xp  = x2b   + ((size_t)(b * Lm + l0)) * Em + e;
    const u16* sp  = skip  + ((size_t)(b * Lm + l0)) * Em + e;
    const float* bp = Bm   + ((size_t)(b * Lm + l0)) * Nm;
    const float* cp = Cm   + ((size_t)(b * Lm + l0)) * Nm;
    u16* yp = yb + ((size_t)(b * Lm + l0)) * Em + e;

    float d_n = bf2f(dp[0]), x_n = bf2f(xp[0]), s_n = bf2f(sp[0]);
    float4 b0n = *(const float4*)(bp + 0), b1n = *(const float4*)(bp + 4);
    float4 b2n = *(const float4*)(bp + 8), b3n = *(const float4*)(bp + 12);
    float4 c0n = *(const float4*)(cp + 0), c1n = *(const float4*)(cp + 4);
    float4 c2n = *(const float4*)(cp + 8), c3n = *(const float4*)(cp + 12);

    #pragma unroll 1
    for (int l = 0; l < CLEN; ++l) {
        float d = d_n, xv = x_n, sv = s_n;
        float4 b0 = b0n, b1 = b1n, b2 = b2n, b3 = b3n;
        float4 c0 = c0n, c1 = c1n, c2 = c2n, c3 = c3n;
        if (l < CLEN - 1) {
            d_n = bf2f(dp[(size_t)(l + 1) * Em]); x_n = bf2f(xp[(size_t)(l + 1) * Em]);
            s_n = bf2f(sp[(size_t)(l + 1) * Em]);
            const float* nb = bp + (size_t)(l + 1) * Nm;
            b0n = *(const float4*)(nb); b1n = *(const float4*)(nb + 4);
            b2n = *(const float4*)(nb + 8); b3n = *(const float4*)(nb + 12);
            const float* nc = cp + (size_t)(l + 1) * Nm;
            c0n = *(const float4*)(nc); c1n = *(const float4*)(nc + 4);
            c2n = *(const float4*)(nc + 8); c3n = *(const float4*)(nc + 12);
        }
        float dx = d * xv;
        float bb[16] = {b0.x,b0.y,b0.z,b0.w, b1.x,b1.y,b1.z,b1.w,
                        b2.x,b2.y,b2.z,b2.w, b3.x,b3.y,b3.z,b3.w};
        float cc[16] = {c0.x,c0.y,c0.z,c0.w, c1.x,c1.y,c1.z,c1.w,
                        c2.x,c2.y,c2.z,c2.w, c3.x,c3.y,c3.z,c3.w};
        float yv = 0.f;
        #pragma unroll
        for (int k = 0; k < 16; ++k) {
            float a = __expf(d * A[k]);
            h[k] = a * h[k] + bb[k] * dx;
            yv += h[k] * cc[k];
        }
        float sig = 1.f / (1.f + __expf(-sv));
        yp[(size_t)l * Em] = f2bf((yv + xv * wd) * (sv * sig));
    }
}

extern "C" void kernel_launch(void* const* d_in, const int* in_sizes, int n_in,
                              void* d_out, int out_size, void* d_ws, size_t ws_size,
                              hipStream_t stream) {
    const float* resid  = (const float*)d_in[0];
    const float* norm_w = (const float*)d_in[2];
    const float* skip_w = (const float*)d_in[3];
    const float* in_w   = (const float*)d_in[4];
    const float* conv_w = (const float*)d_in[5];
    const float* conv_b = (const float*)d_in[6];
    const float* wd1    = (const float*)d_in[7];
    const float* wd2_w  = (const float*)d_in[8];
    const float* wd2_b  = (const float*)d_in[9];
    const float* wb     = (const float*)d_in[10];
    const float* wc     = (const float*)d_in[11];
    const float* A_log  = (const float*)d_in[12];
    const float* W_D    = (const float*)d_in[13];
    const float* out_w  = (const float*)d_in[14];
    float* out = (float*)d_out;

    float* ws = (float*)d_ws;
    float* region0 = ws; ws += 3 * 1024 * 1024;
    u16* x_bf      = (u16*)region0;
    u16* skip_w_bf = (u16*)(region0 + 1024 * 1024);
    u16* in_w_bf   = (u16*)(region0 + 2 * 1024 * 1024);
    u16* out_w_bf  = (u16*)ws; ws += 1024 * 1024;
    u16* wd2_bf    = (u16*)ws; ws += 65536;
    u16* d1_bf     = (u16*)ws; ws += 65536;
    u16* wtb       = (u16*)ws; ws += 131072;       // [128][2048] bf16
    float* h_endb  = ws; ws += 4 * 1024 * 1024;    // [NCH=64][B][16][E]
    float* Pbuf    = ws; ws += 4 * 1024 * 1024;
    u16* Cpart16   = (u16*)ws; ws += (size_t)KS * Mrows * 128 / 2;   // bf16 partials
    u16* skip_bf   = (u16*)ws; ws += (size_t)Mrows * Em / 2;
    u16* xi_bf     = (u16*)ws; ws += (size_t)Mrows * Em / 2;         // reused as delta
    u16* x2_bf     = (u16*)ws; ws += (size_t)Mrows * Em / 2;
    u16* yb_bf     = (u16*)ws; ws += (size_t)Mrows * Em / 2;
    u16* OutPart16 = (u16*)ws; ws += (size_t)KSO * Mrows * Dm / 2;   // bf16 partials
    float* Bmb     = ws; ws += (size_t)Mrows * Nm;
    float* Cmb     = ws; ws += (size_t)Mrows * Nm;
    u16* delta16   = xi_bf;   // xi dead after conv

    const int M = Mrows;

    // merged weight prep + rmsnorm (one dispatch)
    prep_rms_kernel<<<PREPB + M, 256, 0, stream>>>(
        skip_w, in_w, out_w, wd2_w, wb, wc, wd1, resid, norm_w,
        skip_w_bf, in_w_bf, out_w_bf, wd2_bf, wtb, x_bf);

    // fused: [skip | xi] = x @ [skip_w; in_w]^T  (128x64 db, 1024 blocks, bf16 out)
    gemm_db<<<dim3(2 * Em / 64, M / 128, 1), 256, 0, stream>>>(
        x_bf, skip_w_bf, nullptr, (float*)skip_bf, (float*)xi_bf, Em, M, 2 * Em, Dm, Dm, 2);

    conv_silu_kernel<<<(M * Em) / 256, 256, 0, stream>>>(xi_bf, conv_w, conv_b, x2_bf, M * Em);

    // Bm/Cm/d1: x2 @ wtb^T, split-K=16, tiny-K path (4 stages, 1 barrier)
    gemm_smallk<<<dim3(128 / 64, M / 128, KS), 256, 0, stream>>>(
        x2_bf, wtb, nullptr, Cpart16, M, 128, Em, Em / KS, 0);
    small_reduce_kernel<<<(M * 128) / 256, 256, 0, stream>>>(Cpart16, Bmb, Cmb, d1_bf);

    // delta = softplus(d1 @ wd2^T + b), tiny-K path (2 stages, 1 barrier), bf16 out
    gemm_smallk<<<dim3(Em / 64, M / 128, 1), 256, 0, stream>>>(
        d1_bf, wd2_bf, wd2_b, delta16, M, Em, DDm, DDm, 1);

    // chunked scan: 1024 blocks each for scan1/scan3 (CLEN=16, NCH=64)
    scan1_kernel<<<Bb * NCH * 8, 256, 0, stream>>>(delta16, x2_bf, Bmb, A_log, h_endb, Pbuf);
    scan2_kernel<<<65536 / 256, 256, 0, stream>>>(h_endb, Pbuf);
    scan3_kernel<<<Bb * NCH * 8, 256, 0, stream>>>(delta16, x2_bf, Bmb, Cmb, A_log, h_endb,
                                                   skip_bf, W_D, yb_bf);

    // out partials: yb @ out_w^T, split-K=4 via z, bf16 partials
    gemm_db<<<dim3(Dm / 64, M / 128, KSO), 256, 0, stream>>>(
        yb_bf, out_w_bf, nullptr, (float*)OutPart16, nullptr, 0, M, Dm, Em, Em / KSO, 2);
    out_reduce_kernel<<<(M * Dm / 4) / 256, 256, 0, stream>>>(OutPart16, resid, out);
}